// Round 1
// baseline (392.828 us; speedup 1.0000x reference)
//
#include <hip/hip_runtime.h>
#include <math.h>

#define BATCH 8
#define CI    256
#define HWSZ  1600
#define DDIM  128
#define NHEAD 8
#define DH    16
#define NPTS  32768
#define MCHUNK 400

// ---------------- K1: linear1 + l2norm -> tok head-major [B,8,1600,16] ----
__global__ __launch_bounds__(256) void k1_linear1(
    const float* __restrict__ img, const float* __restrict__ W1,
    const float* __restrict__ b1, float* __restrict__ tokh) {
  __shared__ float As[32][32];    // [k][n]
  __shared__ float Ws[32][128];   // [k][d]
  int t = threadIdx.x;
  int blk = blockIdx.x;
  int b = blk / 50;
  int n0 = (blk % 50) * 32;
  int tn = t >> 5;   // 0..7 -> rows tn*4..tn*4+3
  int td = t & 31;   // d = td + 32j
  float acc[4][4];
#pragma unroll
  for (int i = 0; i < 4; i++)
#pragma unroll
    for (int j = 0; j < 4; j++) acc[i][j] = 0.f;
  const float* Ab = img + (size_t)b * CI * HWSZ;
  int ka = t >> 3, na = (t & 7) * 4;
  for (int k0 = 0; k0 < CI; k0 += 32) {
    float4 va = *(const float4*)(Ab + (size_t)(k0 + ka) * HWSZ + n0 + na);
    *(float4*)&As[ka][na] = va;
#pragma unroll
    for (int j = 0; j < 4; j++) {
      int idx = t * 4 + j * 1024;
      int k = idx >> 7, d = idx & 127;
      *(float4*)&Ws[k][d] = *(const float4*)(W1 + (size_t)(k0 + k) * DDIM + d);
    }
    __syncthreads();
#pragma unroll
    for (int k = 0; k < 32; k++) {
      float4 a = *(const float4*)&As[k][tn * 4];
      float w0 = Ws[k][td], w1 = Ws[k][td + 32], w2 = Ws[k][td + 64], w3 = Ws[k][td + 96];
      acc[0][0] += a.x * w0; acc[0][1] += a.x * w1; acc[0][2] += a.x * w2; acc[0][3] += a.x * w3;
      acc[1][0] += a.y * w0; acc[1][1] += a.y * w1; acc[1][2] += a.y * w2; acc[1][3] += a.y * w3;
      acc[2][0] += a.z * w0; acc[2][1] += a.z * w1; acc[2][2] += a.z * w2; acc[2][3] += a.z * w3;
      acc[3][0] += a.w * w0; acc[3][1] += a.w * w1; acc[3][2] += a.w * w2; acc[3][3] += a.w * w3;
    }
    __syncthreads();
  }
  float bb0 = b1[td], bb1 = b1[td + 32], bb2 = b1[td + 64], bb3 = b1[td + 96];
#pragma unroll
  for (int i = 0; i < 4; i++) {
    acc[i][0] += bb0; acc[i][1] += bb1; acc[i][2] += bb2; acc[i][3] += bb3;
    float p = acc[i][0]*acc[i][0] + acc[i][1]*acc[i][1] + acc[i][2]*acc[i][2] + acc[i][3]*acc[i][3];
    p += __shfl_xor(p, 1);  p += __shfl_xor(p, 2);  p += __shfl_xor(p, 4);
    p += __shfl_xor(p, 8);  p += __shfl_xor(p, 16);
    float sc = 1.f / fmaxf(sqrtf(p), 1e-12f);
    int n = n0 + tn * 4 + i;
#pragma unroll
    for (int j = 0; j < 4; j++) {
      int d = td + 32 * j;
      int h = d >> 4, dh = d & 15;
      tokh[(((size_t)b * NHEAD + h) * HWSZ + n) * DH + dh] = acc[i][j] * sc;
    }
  }
}

// ---------------- K2: per-(b,h) self-attention (no-max online softmax) ----
__global__ __launch_bounds__(256) void k2_attn(const float* __restrict__ tokh,
                                               float* __restrict__ aout) {
  __shared__ float kv[MCHUNK * DH];   // 25.6 KB
  int bh = blockIdx.x;
  int b = bh >> 3, h = bh & 7;
  int t = threadIdx.x;
  const float* src = tokh + (size_t)bh * (HWSZ * DH);
  int n = blockIdx.y * 256 + t;
  bool act = n < HWSZ;
  int nn = act ? n : 0;
  float q[16], o[16];
#pragma unroll
  for (int j = 0; j < 4; j++) {
    float4 v = *(const float4*)(src + (size_t)nn * DH + j * 4);
    q[j*4+0] = v.x * 0.25f; q[j*4+1] = v.y * 0.25f;   // fold dh^-0.5 into q
    q[j*4+2] = v.z * 0.25f; q[j*4+3] = v.w * 0.25f;
  }
#pragma unroll
  for (int d = 0; d < 16; d++) o[d] = 0.f;
  float den = 0.f;
  for (int m0 = 0; m0 < HWSZ; m0 += MCHUNK) {
    __syncthreads();
    for (int i = t; i < MCHUNK * DH / 4; i += 256)
      *(float4*)&kv[i * 4] = *(const float4*)(src + (size_t)m0 * DH + (size_t)i * 4);
    __syncthreads();
#pragma unroll 2
    for (int m = 0; m < MCHUNK; m++) {
      float4 k0 = *(const float4*)&kv[m * 16 + 0];
      float4 k1 = *(const float4*)&kv[m * 16 + 4];
      float4 k2 = *(const float4*)&kv[m * 16 + 8];
      float4 k3 = *(const float4*)&kv[m * 16 + 12];
      float s = q[0]*k0.x + q[1]*k0.y + q[2]*k0.z + q[3]*k0.w
              + q[4]*k1.x + q[5]*k1.y + q[6]*k1.z + q[7]*k1.w
              + q[8]*k2.x + q[9]*k2.y + q[10]*k2.z + q[11]*k2.w
              + q[12]*k3.x + q[13]*k3.y + q[14]*k3.z + q[15]*k3.w;
      float e = __expf(s);          // |s| <= 0.25: safe without max-sub
      den += e;
      o[0]  += e * k0.x; o[1]  += e * k0.y; o[2]  += e * k0.z; o[3]  += e * k0.w;
      o[4]  += e * k1.x; o[5]  += e * k1.y; o[6]  += e * k1.z; o[7]  += e * k1.w;
      o[8]  += e * k2.x; o[9]  += e * k2.y; o[10] += e * k2.z; o[11] += e * k2.w;
      o[12] += e * k3.x; o[13] += e * k3.y; o[14] += e * k3.z; o[15] += e * k3.w;
    }
  }
  if (act) {
    float inv = 1.f / den;
    float* dst = aout + ((size_t)b * HWSZ + n) * DDIM + h * DH;
#pragma unroll
    for (int j = 0; j < 4; j++) {
      float4 v = make_float4(o[j*4]*inv, o[j*4+1]*inv, o[j*4+2]*inv, o[j*4+3]*inv);
      *(float4*)(dst + j * 4) = v;
    }
  }
}

// ---------------- K3: linear2 + transpose store + image GeM partials -----
__global__ __launch_bounds__(256) void k3_linear2(
    const float* __restrict__ aout, const float* __restrict__ W2,
    const float* __restrict__ b2, float* __restrict__ img_out,
    float* __restrict__ gacc) {
  __shared__ float As[32][32];     // [k][n]
  __shared__ float Ws[32][256];    // [k][ci]
  __shared__ float gs[256];
  int t = threadIdx.x;
  int blk = blockIdx.x;
  int b = blk / 50;
  int n0 = (blk % 50) * 32;
  int tn = t >> 5, tc = t & 31;
  gs[t] = 0.f;
  float acc[4][8];
#pragma unroll
  for (int i = 0; i < 4; i++)
#pragma unroll
    for (int j = 0; j < 8; j++) acc[i][j] = 0.f;
  const float* Ab = aout + (size_t)b * HWSZ * DDIM;
  int nn = t >> 3, k4 = (t & 7) * 4;
  for (int k0 = 0; k0 < DDIM; k0 += 32) {
    float4 va = *(const float4*)(Ab + (size_t)(n0 + nn) * DDIM + k0 + k4);
    As[k4 + 0][nn] = va.x; As[k4 + 1][nn] = va.y;
    As[k4 + 2][nn] = va.z; As[k4 + 3][nn] = va.w;
#pragma unroll
    for (int j = 0; j < 8; j++) {
      int idx = t * 4 + j * 1024;
      int k = idx >> 8, c = idx & 255;
      *(float4*)&Ws[k][c] = *(const float4*)(W2 + (size_t)(k0 + k) * CI + c);
    }
    __syncthreads();
#pragma unroll
    for (int k = 0; k < 32; k++) {
      float4 a = *(const float4*)&As[k][tn * 4];
#pragma unroll
      for (int j = 0; j < 8; j++) {
        float w = Ws[k][tc + 32 * j];
        acc[0][j] += a.x * w; acc[1][j] += a.y * w;
        acc[2][j] += a.z * w; acc[3][j] += a.w * w;
      }
    }
    __syncthreads();
  }
#pragma unroll
  for (int j = 0; j < 8; j++) {
    int ci = tc + 32 * j;
    float bb = b2[ci];
    float4 v;
    v.x = acc[0][j] + bb; v.y = acc[1][j] + bb;
    v.z = acc[2][j] + bb; v.w = acc[3][j] + bb;
    *(float4*)(img_out + ((size_t)b * CI + ci) * HWSZ + n0 + tn * 4) = v;
    float c0 = fmaxf(v.x, 1e-6f), c1 = fmaxf(v.y, 1e-6f);
    float c2 = fmaxf(v.z, 1e-6f), c3 = fmaxf(v.w, 1e-6f);
    atomicAdd(&gs[ci], c0*c0*c0 + c1*c1*c1 + c2*c2*c2 + c3*c3*c3);
  }
  __syncthreads();
  atomicAdd(&gacc[b * CI + t], gs[t]);
}

// ---------------- K4: cloud l2norm + segment GeM partials ----------------
__global__ __launch_bounds__(256) void k4_cloud(
    const float* __restrict__ cf, const int* __restrict__ bids,
    float* __restrict__ cloud_out, float* __restrict__ cacc,
    float* __restrict__ cnt) {
  __shared__ float ga[BATCH * DDIM];
  __shared__ float gc[BATCH];
  int t = threadIdx.x;
  for (int i = t; i < BATCH * DDIM; i += 256) ga[i] = 0.f;
  if (t < BATCH) gc[t] = 0.f;
  __syncthreads();
  int r = blockIdx.x * 64 + (t >> 2);
  int dq = (t & 3) * 32;
  const float* row = cf + (size_t)r * DDIM + dq;
  float4 v[8];
  float ss = 0.f;
#pragma unroll
  for (int j = 0; j < 8; j++) {
    v[j] = *(const float4*)(row + j * 4);
    ss += v[j].x*v[j].x + v[j].y*v[j].y + v[j].z*v[j].z + v[j].w*v[j].w;
  }
  ss += __shfl_xor(ss, 1);
  ss += __shfl_xor(ss, 2);
  float sc = 1.f / fmaxf(sqrtf(ss), 1e-12f);
  int bid = bids[r];
  if ((t & 3) == 0) atomicAdd(&gc[bid], 1.f);
  float* orow = cloud_out + (size_t)r * DDIM + dq;
  float* gb = &ga[bid * DDIM + dq];
#pragma unroll
  for (int j = 0; j < 8; j++) {
    float4 y;
    y.x = v[j].x * sc; y.y = v[j].y * sc; y.z = v[j].z * sc; y.w = v[j].w * sc;
    *(float4*)(orow + j * 4) = y;
    float c0 = fmaxf(y.x, 1e-6f), c1 = fmaxf(y.y, 1e-6f);
    float c2 = fmaxf(y.z, 1e-6f), c3 = fmaxf(y.w, 1e-6f);
    atomicAdd(&gb[j*4+0], c0*c0*c0);
    atomicAdd(&gb[j*4+1], c1*c1*c1);
    atomicAdd(&gb[j*4+2], c2*c2*c2);
    atomicAdd(&gb[j*4+3], c3*c3*c3);
  }
  __syncthreads();
  for (int i = t; i < BATCH * DDIM; i += 256) atomicAdd(&cacc[i], ga[i]);
  if (t < BATCH) atomicAdd(&cnt[t], gc[t]);
}

// ---------------- K5: finalize GeM ---------------------------------------
__global__ __launch_bounds__(256) void k5_final(
    const float* __restrict__ gacc, const float* __restrict__ cacc,
    const float* __restrict__ cnt, float* __restrict__ image_gem,
    float* __restrict__ cloud_gem) {
  int i = blockIdx.x * 256 + threadIdx.x;
  if (i < BATCH * CI) {
    image_gem[i] = powf(gacc[i] * (1.f / (float)HWSZ), 1.f / 3.f);
  } else if (i < BATCH * CI + BATCH * DDIM) {
    int j = i - BATCH * CI;
    int b = j >> 7;
    cloud_gem[j] = powf(cacc[j] / fmaxf(cnt[b], 1.f), 1.f / 3.f);
  }
}

extern "C" void kernel_launch(void* const* d_in, const int* in_sizes, int n_in,
                              void* d_out, int out_size, void* d_ws, size_t ws_size,
                              hipStream_t stream) {
  const float* image_feat = (const float*)d_in[0];
  const float* cloud_feat = (const float*)d_in[1];
  const int*   cloud_bids = (const int*)d_in[2];
  const float* W1 = (const float*)d_in[3];
  const float* b1 = (const float*)d_in[4];
  const float* W2 = (const float*)d_in[5];
  const float* b2 = (const float*)d_in[6];

  float* out = (float*)d_out;
  float* img_out   = out;                                  // [8,256,40,40]
  float* cloud_out = out + 3276800;                        // [32768,128]
  float* image_gem = out + 3276800 + 4194304;              // [8,256]
  float* cloud_gem = image_gem + 2048;                     // [8,128]

  float* tokh = (float*)d_ws;                              // [8,8,1600,16]
  float* aout = tokh + 1638400;                            // [8,1600,128]
  float* gacc = aout + 1638400;                            // [8,256]
  float* cacc = gacc + 2048;                               // [8,128]
  float* cnt  = cacc + 1024;                               // [8]

  hipMemsetAsync(gacc, 0, (2048 + 1024 + 8) * sizeof(float), stream);

  k1_linear1<<<dim3(400), dim3(256), 0, stream>>>(image_feat, W1, b1, tokh);
  k2_attn<<<dim3(64, 7), dim3(256), 0, stream>>>(tokh, aout);
  k3_linear2<<<dim3(400), dim3(256), 0, stream>>>(aout, W2, b2, img_out, gacc);
  k4_cloud<<<dim3(512), dim3(256), 0, stream>>>(cloud_feat, cloud_bids,
                                                cloud_out, cacc, cnt);
  k5_final<<<dim3(12), dim3(256), 0, stream>>>(gacc, cacc, cnt,
                                               image_gem, cloud_gem);
}

// Round 3
// 218.552 us; speedup vs baseline: 1.7974x; 1.7974x over previous
//
#include <hip/hip_runtime.h>
#include <math.h>

#define BATCH 8
#define CI    256
#define HWSZ  1600
#define DDIM  128
#define NHEAD 8
#define DH    16
#define NPTS  32768
#define MCHUNK 400

typedef __attribute__((ext_vector_type(4))) short s16x4;
typedef __attribute__((ext_vector_type(4))) float f32x4;

#if defined(__HIP_DEVICE_COMPILE__)
  #if __has_builtin(__builtin_amdgcn_mfma_f32_16x16x16bf16_1k)
    #define MFMA16(a, b, c) __builtin_amdgcn_mfma_f32_16x16x16bf16_1k(a, b, c, 0, 0, 0)
  #elif __has_builtin(__builtin_amdgcn_mfma_f32_16x16x16_bf16)
    #define MFMA16(a, b, c) __builtin_amdgcn_mfma_f32_16x16x16_bf16(a, b, c, 0, 0, 0)
  #else
    #error "no 16x16x16 bf16 mfma builtin on this device target"
  #endif
  #if __has_builtin(__builtin_amdgcn_exp2f)
    #define EXP2(x) __builtin_amdgcn_exp2f(x)
  #else
    #define EXP2(x) exp2f(x)
  #endif
#else
  // host pass: type-correct stubs, never executed
  #define MFMA16(a, b, c) (c)
  #define EXP2(x) (x)
#endif

__device__ __forceinline__ unsigned short f2bf(float x) {
  unsigned int u = __float_as_uint(x);
  unsigned int r = (u + 0x7FFFu + ((u >> 16) & 1u)) >> 16;   // RNE
  return (unsigned short)r;
}
__device__ __forceinline__ float bf2f(unsigned short u) {
  return __uint_as_float(((unsigned int)u) << 16);
}

// ---------------- K1: linear1 + l2norm -> tok head-major bf16 [B,8,1600,16]
__global__ __launch_bounds__(256) void k1_linear1(
    const float* __restrict__ img, const float* __restrict__ W1,
    const float* __restrict__ b1, unsigned short* __restrict__ tokh) {
  __shared__ float As[32][32];    // [k][n]
  __shared__ float Ws[32][128];   // [k][d]
  int t = threadIdx.x;
  int blk = blockIdx.x;
  int b = blk / 50;
  int n0 = (blk % 50) * 32;
  int tn = t >> 5;   // 0..7 -> rows tn*4..tn*4+3
  int td = t & 31;   // d = td + 32j
  float acc[4][4];
#pragma unroll
  for (int i = 0; i < 4; i++)
#pragma unroll
    for (int j = 0; j < 4; j++) acc[i][j] = 0.f;
  const float* Ab = img + (size_t)b * CI * HWSZ;
  int ka = t >> 3, na = (t & 7) * 4;
  for (int k0 = 0; k0 < CI; k0 += 32) {
    float4 va = *(const float4*)(Ab + (size_t)(k0 + ka) * HWSZ + n0 + na);
    *(float4*)&As[ka][na] = va;
#pragma unroll
    for (int j = 0; j < 4; j++) {
      int idx = t * 4 + j * 1024;
      int k = idx >> 7, d = idx & 127;
      *(float4*)&Ws[k][d] = *(const float4*)(W1 + (size_t)(k0 + k) * DDIM + d);
    }
    __syncthreads();
#pragma unroll
    for (int k = 0; k < 32; k++) {
      float4 a = *(const float4*)&As[k][tn * 4];
      float w0 = Ws[k][td], w1 = Ws[k][td + 32], w2 = Ws[k][td + 64], w3 = Ws[k][td + 96];
      acc[0][0] += a.x * w0; acc[0][1] += a.x * w1; acc[0][2] += a.x * w2; acc[0][3] += a.x * w3;
      acc[1][0] += a.y * w0; acc[1][1] += a.y * w1; acc[1][2] += a.y * w2; acc[1][3] += a.y * w3;
      acc[2][0] += a.z * w0; acc[2][1] += a.z * w1; acc[2][2] += a.z * w2; acc[2][3] += a.z * w3;
      acc[3][0] += a.w * w0; acc[3][1] += a.w * w1; acc[3][2] += a.w * w2; acc[3][3] += a.w * w3;
    }
    __syncthreads();
  }
  float bb0 = b1[td], bb1 = b1[td + 32], bb2 = b1[td + 64], bb3 = b1[td + 96];
#pragma unroll
  for (int i = 0; i < 4; i++) {
    acc[i][0] += bb0; acc[i][1] += bb1; acc[i][2] += bb2; acc[i][3] += bb3;
    float p = acc[i][0]*acc[i][0] + acc[i][1]*acc[i][1] + acc[i][2]*acc[i][2] + acc[i][3]*acc[i][3];
    p += __shfl_xor(p, 1);  p += __shfl_xor(p, 2);  p += __shfl_xor(p, 4);
    p += __shfl_xor(p, 8);  p += __shfl_xor(p, 16);
    float sc = 1.f / fmaxf(sqrtf(p), 1e-12f);
    int n = n0 + tn * 4 + i;
#pragma unroll
    for (int j = 0; j < 4; j++) {
      int d = td + 32 * j;
      int h = d >> 4, dh = d & 15;
      tokh[(((size_t)b * NHEAD + h) * HWSZ + n) * DH + dh] = f2bf(acc[i][j] * sc);
    }
  }
}

// ---------------- K2: MFMA flash attention (no-max online softmax) -------
// S^T = mfma(A=K-frag, B=Q-frag): D rows = key (quad*4+reg), cols = query
// (lane&15). That D-layout IS the B-operand layout for the PV mfma, so P
// needs no cross-lane transform. V is staged transposed in LDS for the
// A-operand of PV. Softmax scale folded into Q as 0.25*log2(e) -> exp2.
#define NKC      400          // keys per staged chunk (1600 = 4*400)
#define XK_STR   24           // Xk row stride in shorts (48 B: 16B-aligned, conflict-free)
#define VT_STR   408          // Vt row stride in shorts (breaks pow2 banks)
__global__ __launch_bounds__(256) void k2_attn(
    const unsigned short* __restrict__ tokh, float* __restrict__ aout) {
  __shared__ unsigned short sXk[NKC * XK_STR];   // 19200 B row-major keys
  __shared__ unsigned short sVt[16 * VT_STR];    // 13056 B transposed V
  const int bh = blockIdx.x;
  const int b = bh >> 3, h = bh & 7;
  const int t = threadIdx.x;
  const int lane = t & 63;
  const int w = t >> 6;
  const int lm = lane & 15;        // query col / d row
  const int qd = lane >> 4;        // quad
  const unsigned short* tok = tokh + (size_t)bh * (HWSZ * DH);
  const int qw = blockIdx.y * 256 + w * 64;      // this wave's 64 q rows
  const bool active = qw < HWSZ;

  const float SCL = 0.25f * 1.44269504088896f;   // dh^-0.5 * log2(e)
  s16x4 qf[4];
  f32x4 oacc[4];
  float den[4];
  if (active) {
#pragma unroll
    for (int s = 0; s < 4; s++) {
      const unsigned short* qs = tok + (size_t)(qw + s * 16 + lm) * DH + 4 * qd;
      s16x4 raw = *(const s16x4*)qs;
      s16x4 q;
#pragma unroll
      for (int i = 0; i < 4; i++)
        q[i] = (short)f2bf(bf2f((unsigned short)raw[i]) * SCL);
      qf[s] = q;
      oacc[s] = (f32x4){0.f, 0.f, 0.f, 0.f};
      den[s] = 0.f;
    }
  }

  for (int c = 0; c < 4; c++) {
    __syncthreads();
    // stage chunk c: rows c*400 .. c*400+399 into Xk (row-major, padded)
    // and Vt (transposed)
    for (int r = t; r < NKC; r += 256) {
      const uint4* src = (const uint4*)(tok + (size_t)(c * NKC + r) * DH);
      union { uint4 u4[2]; unsigned short us[16]; } uu;
      uu.u4[0] = src[0]; uu.u4[1] = src[1];
      *(uint4*)&sXk[r * XK_STR]     = uu.u4[0];
      *(uint4*)&sXk[r * XK_STR + 8] = uu.u4[1];
#pragma unroll
      for (int d = 0; d < 16; d++) sVt[d * VT_STR + r] = uu.us[d];
    }
    __syncthreads();
    if (active) {
#pragma unroll 1
      for (int st = 0; st < NKC / 16; st++) {
        int n0 = st * 16;
        s16x4 kf = *(const s16x4*)&sXk[(n0 + lm) * XK_STR + 4 * qd];
        s16x4 vf = *(const s16x4*)&sVt[lm * VT_STR + n0 + 4 * qd];
#pragma unroll
        for (int s = 0; s < 4; s++) {
          f32x4 sc = MFMA16(kf, qf[s], ((f32x4){0.f, 0.f, 0.f, 0.f}));
          float e0 = EXP2(sc.x), e1 = EXP2(sc.y), e2 = EXP2(sc.z), e3 = EXP2(sc.w);
          den[s] += (e0 + e1) + (e2 + e3);
          s16x4 pf = { (short)f2bf(e0), (short)f2bf(e1),
                       (short)f2bf(e2), (short)f2bf(e3) };
          oacc[s] = MFMA16(vf, pf, oacc[s]);
        }
      }
    }
  }

  if (active) {
#pragma unroll
    for (int s = 0; s < 4; s++) {
      float d = den[s];
      d += __shfl_xor(d, 16);
      d += __shfl_xor(d, 32);
      float inv = 1.f / d;
      float4 o;
      o.x = oacc[s].x * inv; o.y = oacc[s].y * inv;
      o.z = oacc[s].z * inv; o.w = oacc[s].w * inv;
      float* dst = aout + ((size_t)b * HWSZ + qw + s * 16 + lm) * DDIM
                   + h * DH + 4 * qd;
      *(float4*)dst = o;
    }
  }
}

// ---------------- K3: linear2 + transpose store + image GeM partials -----
__global__ __launch_bounds__(256) void k3_linear2(
    const float* __restrict__ aout, const float* __restrict__ W2,
    const float* __restrict__ b2, float* __restrict__ img_out,
    float* __restrict__ gacc) {
  __shared__ float As[32][32];     // [k][n]
  __shared__ float Ws[32][256];    // [k][ci]
  __shared__ float gs[256];
  int t = threadIdx.x;
  int blk = blockIdx.x;
  int b = blk / 50;
  int n0 = (blk % 50) * 32;
  int tn = t >> 5, tc = t & 31;
  gs[t] = 0.f;
  float acc[4][8];
#pragma unroll
  for (int i = 0; i < 4; i++)
#pragma unroll
    for (int j = 0; j < 8; j++) acc[i][j] = 0.f;
  const float* Ab = aout + (size_t)b * HWSZ * DDIM;
  int nn = t >> 3, k4 = (t & 7) * 4;
  for (int k0 = 0; k0 < DDIM; k0 += 32) {
    float4 va = *(const float4*)(Ab + (size_t)(n0 + nn) * DDIM + k0 + k4);
    As[k4 + 0][nn] = va.x; As[k4 + 1][nn] = va.y;
    As[k4 + 2][nn] = va.z; As[k4 + 3][nn] = va.w;
#pragma unroll
    for (int j = 0; j < 8; j++) {
      int idx = t * 4 + j * 1024;
      int k = idx >> 8, c = idx & 255;
      *(float4*)&Ws[k][c] = *(const float4*)(W2 + (size_t)(k0 + k) * CI + c);
    }
    __syncthreads();
#pragma unroll
    for (int k = 0; k < 32; k++) {
      float4 a = *(const float4*)&As[k][tn * 4];
#pragma unroll
      for (int j = 0; j < 8; j++) {
        float w = Ws[k][tc + 32 * j];
        acc[0][j] += a.x * w; acc[1][j] += a.y * w;
        acc[2][j] += a.z * w; acc[3][j] += a.w * w;
      }
    }
    __syncthreads();
  }
#pragma unroll
  for (int j = 0; j < 8; j++) {
    int ci = tc + 32 * j;
    float bb = b2[ci];
    float4 v;
    v.x = acc[0][j] + bb; v.y = acc[1][j] + bb;
    v.z = acc[2][j] + bb; v.w = acc[3][j] + bb;
    *(float4*)(img_out + ((size_t)b * CI + ci) * HWSZ + n0 + tn * 4) = v;
    float c0 = fmaxf(v.x, 1e-6f), c1 = fmaxf(v.y, 1e-6f);
    float c2 = fmaxf(v.z, 1e-6f), c3 = fmaxf(v.w, 1e-6f);
    atomicAdd(&gs[ci], c0*c0*c0 + c1*c1*c1 + c2*c2*c2 + c3*c3*c3);
  }
  __syncthreads();
  atomicAdd(&gacc[b * CI + t], gs[t]);
}

// ---------------- K4: cloud l2norm + segment GeM partials ----------------
__global__ __launch_bounds__(256) void k4_cloud(
    const float* __restrict__ cf, const int* __restrict__ bids,
    float* __restrict__ cloud_out, float* __restrict__ cacc,
    float* __restrict__ cnt) {
  __shared__ float ga[BATCH * DDIM];
  __shared__ float gc[BATCH];
  int t = threadIdx.x;
  for (int i = t; i < BATCH * DDIM; i += 256) ga[i] = 0.f;
  if (t < BATCH) gc[t] = 0.f;
  __syncthreads();
  int r = blockIdx.x * 64 + (t >> 2);
  int dq = (t & 3) * 32;
  const float* row = cf + (size_t)r * DDIM + dq;
  float4 v[8];
  float ss = 0.f;
#pragma unroll
  for (int j = 0; j < 8; j++) {
    v[j] = *(const float4*)(row + j * 4);
    ss += v[j].x*v[j].x + v[j].y*v[j].y + v[j].z*v[j].z + v[j].w*v[j].w;
  }
  ss += __shfl_xor(ss, 1);
  ss += __shfl_xor(ss, 2);
  float sc = 1.f / fmaxf(sqrtf(ss), 1e-12f);
  int bid = bids[r];
  if ((t & 3) == 0) atomicAdd(&gc[bid], 1.f);
  float* orow = cloud_out + (size_t)r * DDIM + dq;
  float* gb = &ga[bid * DDIM + dq];
#pragma unroll
  for (int j = 0; j < 8; j++) {
    float4 y;
    y.x = v[j].x * sc; y.y = v[j].y * sc; y.z = v[j].z * sc; y.w = v[j].w * sc;
    *(float4*)(orow + j * 4) = y;
    float c0 = fmaxf(y.x, 1e-6f), c1 = fmaxf(y.y, 1e-6f);
    float c2 = fmaxf(y.z, 1e-6f), c3 = fmaxf(y.w, 1e-6f);
    atomicAdd(&gb[j*4+0], c0*c0*c0);
    atomicAdd(&gb[j*4+1], c1*c1*c1);
    atomicAdd(&gb[j*4+2], c2*c2*c2);
    atomicAdd(&gb[j*4+3], c3*c3*c3);
  }
  __syncthreads();
  for (int i = t; i < BATCH * DDIM; i += 256) atomicAdd(&cacc[i], ga[i]);
  if (t < BATCH) atomicAdd(&cnt[t], gc[t]);
}

// ---------------- K5: finalize GeM ---------------------------------------
__global__ __launch_bounds__(256) void k5_final(
    const float* __restrict__ gacc, const float* __restrict__ cacc,
    const float* __restrict__ cnt, float* __restrict__ image_gem,
    float* __restrict__ cloud_gem) {
  int i = blockIdx.x * 256 + threadIdx.x;
  if (i < BATCH * CI) {
    image_gem[i] = powf(gacc[i] * (1.f / (float)HWSZ), 1.f / 3.f);
  } else if (i < BATCH * CI + BATCH * DDIM) {
    int j = i - BATCH * CI;
    int b = j >> 7;
    cloud_gem[j] = powf(cacc[j] / fmaxf(cnt[b], 1.f), 1.f / 3.f);
  }
}

extern "C" void kernel_launch(void* const* d_in, const int* in_sizes, int n_in,
                              void* d_out, int out_size, void* d_ws, size_t ws_size,
                              hipStream_t stream) {
  const float* image_feat = (const float*)d_in[0];
  const float* cloud_feat = (const float*)d_in[1];
  const int*   cloud_bids = (const int*)d_in[2];
  const float* W1 = (const float*)d_in[3];
  const float* b1 = (const float*)d_in[4];
  const float* W2 = (const float*)d_in[5];
  const float* b2 = (const float*)d_in[6];

  float* out = (float*)d_out;
  float* img_out   = out;                                  // [8,256,40,40]
  float* cloud_out = out + 3276800;                        // [32768,128]
  float* image_gem = out + 3276800 + 4194304;              // [8,256]
  float* cloud_gem = image_gem + 2048;                     // [8,128]

  char* ws = (char*)d_ws;
  unsigned short* tokh = (unsigned short*)ws;              // bf16 [8,8,1600,16] = 3,276,800 B
  float* aout = (float*)(ws + 3276800);                    // f32 [8,1600,128]  = 6,553,600 B
  float* gacc = (float*)(ws + 3276800 + 6553600);          // [8,256]
  float* cacc = gacc + 2048;                               // [8,128]
  float* cnt  = cacc + 1024;                               // [8]

  (void)hipMemsetAsync(gacc, 0, (2048 + 1024 + 8) * sizeof(float), stream);

  k1_linear1<<<dim3(400), dim3(256), 0, stream>>>(image_feat, W1, b1, tokh);
  k2_attn<<<dim3(64, 7), dim3(256), 0, stream>>>(tokh, aout);
  k3_linear2<<<dim3(400), dim3(256), 0, stream>>>(aout, W2, b2, img_out, gacc);
  k4_cloud<<<dim3(512), dim3(256), 0, stream>>>(cloud_feat, cloud_bids,
                                                cloud_out, cacc, cnt);
  k5_final<<<dim3(12), dim3(256), 0, stream>>>(gacc, cacc, cnt,
                                               image_gem, cloud_gem);
}